// Round 11
// baseline (25659.454 us; speedup 1.0000x reference)
//
#include <hip/hip_runtime.h>
#include <math.h>

#define B_    128
#define T_    256
#define DIM_  512
#define HID_  1024
#define OUT_  512
#define TAG_  64
#define K3_   3072

typedef float f32x4 __attribute__((ext_vector_type(4)));
typedef short bf16x8 __attribute__((ext_vector_type(8)));
typedef unsigned uint32x4 __attribute__((ext_vector_type(4)));

#define MFMA(a,b,c) __builtin_amdgcn_mfma_f32_16x16x32_bf16(a,b,c,0,0,0)

__device__ __forceinline__ unsigned short f2b(float f){
    unsigned int u = __float_as_uint(f);
    u = (u + 0x7fffu + ((u >> 16) & 1u)) >> 16;   // RNE
    return (unsigned short)u;
}
__device__ __forceinline__ float hardsig(float x){
    return fminf(fmaxf(0.2f*x + 0.5f, 0.f), 1.f);
}
__device__ __forceinline__ uint32x4 ld16(const void* p){
    return *(const uint32x4*)p;
}
__device__ __forceinline__ uint32x4 pack8f(const float* p){
    float4 a = *(const float4*)p;
    float4 b = *(const float4*)(p + 4);
    uint32x4 r;
    r.x = ((unsigned)f2b(a.y) << 16) | f2b(a.x);
    r.y = ((unsigned)f2b(a.w) << 16) | f2b(a.z);
    r.z = ((unsigned)f2b(b.y) << 16) | f2b(b.x);
    r.w = ((unsigned)f2b(b.w) << 16) | f2b(b.z);
    return r;
}

// ---------- prep kernels ----------
__global__ __launch_bounds__(256) void k_tr(
    unsigned short* __restrict__ dst, int dstride,
    const float* __restrict__ src, int ld, int col_off)
{
    __shared__ float tile[32][33];
    const int kb = blockIdx.x * 32, nb = blockIdx.y * 32;
    const int tx = threadIdx.x & 31, ty = threadIdx.x >> 5;
    #pragma unroll
    for (int i = 0; i < 4; ++i){
        int kl = ty + i*8;
        tile[kl][tx] = src[(size_t)(kb + kl)*ld + col_off + nb + tx];
    }
    __syncthreads();
    #pragma unroll
    for (int i = 0; i < 4; ++i){
        int nl = ty + i*8;
        dst[(size_t)(nb + nl)*dstride + kb + tx] = f2b(tile[tx][nl]);
    }
}
__global__ __launch_bounds__(256) void k_cvtx(
    const float4* __restrict__ src, ushort4* __restrict__ dst, int n4)
{
    int i = blockIdx.x * 256 + threadIdx.x;
    if (i < n4){
        float4 v = src[i];
        ushort4 o;
        o.x = f2b(v.x); o.y = f2b(v.y); o.z = f2b(v.z); o.w = f2b(v.w);
        dst[i] = o;
    }
}
__global__ __launch_bounds__(256) void k_init(
    const float* __restrict__ x0, const float* __restrict__ s0,
    unsigned short* __restrict__ xbufB, float* __restrict__ s_f,
    unsigned short* __restrict__ s_b)
{
    int i = blockIdx.x * 256 + threadIdx.x;
    if (i < B_*OUT_) xbufB[i] = f2b(x0[i]);
    if (i < B_*HID_){ s_f[i] = s0[i]; s_b[i] = f2b(s0[i]); }
}

// ===== phase A: pre/rs — 96 WGs: np (strip of 128 cols) = wg%24, mp = wg/24 =====
__global__ __launch_bounds__(512) void k_gA(
    const unsigned short* __restrict__ xb16, const float* __restrict__ xf, int use_xb,
    const unsigned short* __restrict__ Wcat, const float* __restrict__ bias,
    const unsigned short* __restrict__ xbufB, const unsigned short* __restrict__ s_bb,
    const float* __restrict__ spf,
    unsigned short* __restrict__ rs_bb, float* __restrict__ pre_z,
    float* __restrict__ pre_xs, int t)
{
    __shared__ __align__(16) char smem[131072];
    const int wg   = blockIdx.x;
    const int tid  = threadIdx.x;
    const int lane = tid & 63;
    const int wv   = tid >> 6;
    const int l15  = lane & 15;
    const int kch  = lane >> 4;
    const int mt   = wv >> 2;
    const int ns   = wv & 3;
    const int axor = l15 & 7;

    const int npA = wg % 24, mpA = wg / 24;
    const int m0A = mpA*32, cA = npA*128, nsegA = npA >> 3;   // 0=r 1=z 2=xs

    if (nsegA < 2){
        #pragma unroll
        for (int j = 0; j < 16; ++j){
            const int c = tid + j*512, row = c >> 8, k16 = c & 255;
            const int gr = m0A + row;
            uint32x4 v;
            if (k16 < 64)       v = ld16(xbufB + gr*512 + k16*8);
            else if (k16 < 128){
                if (use_xb)     v = ld16(xb16 + ((size_t)gr*T_ + t)*DIM_ + (k16-64)*8);
                else            v = pack8f(xf + ((size_t)gr*T_ + t)*DIM_ + (k16-64)*8);
            } else              v = ld16(s_bb + gr*1024 + (k16-128)*8);
            *(uint32x4*)(smem + row*4096 + ((k16 ^ (row & 7)) << 4)) = v;
        }
    } else {
        #pragma unroll
        for (int j = 0; j < 8; ++j){
            const int c = tid + j*512, row = c >> 7, k16 = c & 127;
            const int gr = m0A + row;
            uint32x4 v;
            if (k16 < 64)       v = ld16(xbufB + gr*512 + k16*8);
            else {
                if (use_xb)     v = ld16(xb16 + ((size_t)gr*T_ + t)*DIM_ + (k16-64)*8);
                else            v = pack8f(xf + ((size_t)gr*T_ + t)*DIM_ + (k16-64)*8);
            }
            *(uint32x4*)(smem + row*4096 + ((k16 ^ (row & 7)) << 4)) = v;
        }
    }
    __syncthreads();

    const int c0 = cA + ns*32;
    const int kmax = (nsegA < 2) ? 2048 : 1024;
    const unsigned short* bp0 = Wcat + (size_t)(c0 + l15)*2048 + kch*8;
    const unsigned short* bp1 = bp0 + (size_t)16*2048;
    f32x4 acc0 = {0.f,0.f,0.f,0.f}, acc1 = {0.f,0.f,0.f,0.f};
    const int abase = (mt*16 + l15)*4096;
    #pragma unroll 8
    for (int kb = 0; kb < kmax; kb += 32){
        bf16x8 a = *(const bf16x8*)(smem + abase + ((((kb>>3)+kch) ^ axor) << 4));
        acc0 = MFMA(a, *(const bf16x8*)(bp0 + kb), acc0);
        acc1 = MFMA(a, *(const bf16x8*)(bp1 + kb), acc1);
    }
    const int rbA = m0A + mt*16 + kch*4;
    if (nsegA == 0){
        #pragma unroll
        for (int h = 0; h < 2; ++h){
            f32x4 acc = h ? acc1 : acc0;
            const int col = c0 + h*16 + l15;
            const float bv = bias[col];
            #pragma unroll
            for (int q = 0; q < 4; ++q){
                float rs = hardsig(acc[q] + bv) * spf[(size_t)(rbA+q)*1024 + col];
                rs_bb[(size_t)(rbA+q)*1024 + col] = f2b(rs);
            }
        }
    } else if (nsegA == 1){
        #pragma unroll
        for (int h = 0; h < 2; ++h){
            f32x4 acc = h ? acc1 : acc0;
            const int col = c0 + h*16 + l15;
            const float bv = bias[col];
            #pragma unroll
            for (int q = 0; q < 4; ++q)
                pre_z[(size_t)(rbA+q)*1024 + (col - 1024)] = acc[q] + bv;
        }
    } else {
        #pragma unroll
        for (int h = 0; h < 2; ++h){
            f32x4 acc = h ? acc1 : acc0;
            const int col = c0 + h*16 + l15;
            const float bv = bias[col];
            #pragma unroll
            for (int q = 0; q < 4; ++q)
                pre_xs[(size_t)(rbA+q)*1024 + (col - 2048)] = acc[q] + bv;
        }
    }
}

// ===== phase B: s update — 32 WGs: np = wg%8 (128-col strip), mp = wg/8 =====
__global__ __launch_bounds__(512) void k_gB(
    const unsigned short* __restrict__ Ust,
    const unsigned short* __restrict__ rs_bb,
    const float* __restrict__ pre_z, const float* __restrict__ pre_xs,
    const float* __restrict__ spf,
    float* __restrict__ snf, unsigned short* __restrict__ s_bb)
{
    __shared__ __align__(16) char smem[65536];
    const int wg   = blockIdx.x;
    const int tid  = threadIdx.x;
    const int lane = tid & 63;
    const int wv   = tid >> 6;
    const int l15  = lane & 15;
    const int kch  = lane >> 4;
    const int mt   = wv >> 2;
    const int ns   = wv & 3;
    const int axor = l15 & 7;
    const int np = wg % 8, mp = wg / 8;
    const int m0B = mp*32, cB = np*128;

    #pragma unroll
    for (int j = 0; j < 8; ++j){
        const int c = tid + j*512, row = c >> 7, k16 = c & 127;
        uint32x4 v = ld16(rs_bb + (size_t)(m0B+row)*1024 + k16*8);
        *(uint32x4*)(smem + row*2048 + ((k16 ^ (row & 7)) << 4)) = v;
    }
    __syncthreads();

    const int c0 = cB + ns*32;
    const unsigned short* bp0 = Ust + (size_t)(c0 + l15)*1024 + kch*8;
    const unsigned short* bp1 = bp0 + (size_t)16*1024;
    f32x4 acc0 = {0.f,0.f,0.f,0.f}, acc1 = {0.f,0.f,0.f,0.f};
    const int abase = (mt*16 + l15)*2048;
    #pragma unroll 8
    for (int kb = 0; kb < 1024; kb += 32){
        bf16x8 a = *(const bf16x8*)(smem + abase + ((((kb>>3)+kch) ^ axor) << 4));
        acc0 = MFMA(a, *(const bf16x8*)(bp0 + kb), acc0);
        acc1 = MFMA(a, *(const bf16x8*)(bp1 + kb), acc1);
    }
    const int rbB = m0B + mt*16 + kch*4;
    #pragma unroll
    for (int h = 0; h < 2; ++h){
        f32x4 acc = h ? acc1 : acc0;
        const int col = c0 + h*16 + l15;
        #pragma unroll
        for (int q = 0; q < 4; ++q){
            const size_t idx = (size_t)(rbB+q)*1024 + col;
            float z  = hardsig(pre_z[idx]);
            float sv = (1.f - z)*spf[idx] + z*tanhf(pre_xs[idx] + acc[q]);
            snf[idx]  = sv;
            s_bb[idx] = f2b(sv);
        }
    }
}

// ===== phase CD: logits + softmax + Wy head — 8 WGs x 512, 16 full rows each =====
__global__ __launch_bounds__(512) void k_gCD(
    const unsigned short* __restrict__ Wxt,   // [col][1024] bf16
    const unsigned short* __restrict__ s_bb,  // [128][1024] bf16
    const float* __restrict__ bx,
    const float* __restrict__ Wy,             // [512][64] f32
    const float* __restrict__ by,
    unsigned short* __restrict__ xbufB,       // [128][512] bf16
    float* __restrict__ out, int t)
{
    __shared__ __align__(16) char smem[32768];   // A staging: 16 rows x 2048B
    __shared__ float lg[16][516];                // logits (+4 pad vs bank aliasing)
    const int g    = blockIdx.x;      // rows 16g..16g+15
    const int tid  = threadIdx.x;
    const int lane = tid & 63;
    const int wv   = tid >> 6;
    const int l15  = lane & 15;
    const int kch  = lane >> 4;

    // stage 16 rows x 1024 bf16 of s_b, XOR-swizzled
    #pragma unroll
    for (int j = 0; j < 4; ++j){
        const int c = tid + j*512, row = c >> 7, k16 = c & 127;
        uint32x4 v = ld16(s_bb + (size_t)(g*16 + row)*1024 + k16*8);
        *(uint32x4*)(smem + row*2048 + ((k16 ^ (row & 7)) << 4)) = v;
    }
    __syncthreads();

    // GEMM: wave wv covers cols wv*64..+63 (4 streams of 16 cols)
    const int c0 = wv*64;
    const unsigned short* bp0 = Wxt + (size_t)(c0 + l15)*1024 + kch*8;
    const unsigned short* bp1 = bp0 + (size_t)16*1024;
    const unsigned short* bp2 = bp0 + (size_t)32*1024;
    const unsigned short* bp3 = bp0 + (size_t)48*1024;
    f32x4 a0={0.f,0.f,0.f,0.f}, a1={0.f,0.f,0.f,0.f};
    f32x4 a2={0.f,0.f,0.f,0.f}, a3={0.f,0.f,0.f,0.f};
    const int abase = l15*2048;
    const int axor  = l15 & 7;
    #pragma unroll 8
    for (int kb = 0; kb < 1024; kb += 32){
        bf16x8 a = *(const bf16x8*)(smem + abase + ((((kb>>3)+kch) ^ axor) << 4));
        a0 = MFMA(a, *(const bf16x8*)(bp0 + kb), a0);
        a1 = MFMA(a, *(const bf16x8*)(bp1 + kb), a1);
        a2 = MFMA(a, *(const bf16x8*)(bp2 + kb), a2);
        a3 = MFMA(a, *(const bf16x8*)(bp3 + kb), a3);
    }
    // epilogue -> LDS logits (+bx). C row = kch*4+q, col = c0 + 16*h + l15
    #pragma unroll
    for (int q = 0; q < 4; ++q){
        const int row = kch*4 + q;
        lg[row][c0      + l15] = a0[q] + bx[c0      + l15];
        lg[row][c0 + 16 + l15] = a1[q] + bx[c0 + 16 + l15];
        lg[row][c0 + 32 + l15] = a2[q] + bx[c0 + 32 + l15];
        lg[row][c0 + 48 + l15] = a3[q] + bx[c0 + 48 + l15];
    }
    __syncthreads();

    // softmax: 32 threads per row (rows 2w, 2w+1 share wave w)
    const int row = tid >> 5, l32 = tid & 31;
    const int gr  = g*16 + row;
    float v[16];
    float mx = -3.0e38f;
    #pragma unroll
    for (int i = 0; i < 16; ++i){ v[i] = lg[row][l32 + i*32]; mx = fmaxf(mx, v[i]); }
    #pragma unroll
    for (int off = 16; off > 0; off >>= 1) mx = fmaxf(mx, __shfl_xor(mx, off));
    float s = 0.f;
    #pragma unroll
    for (int i = 0; i < 16; ++i){ v[i] = expf(v[i] - mx); s += v[i]; }
    #pragma unroll
    for (int off = 16; off > 0; off >>= 1) s += __shfl_xor(s, off);
    const float inv = 1.f / s;
    #pragma unroll
    for (int i = 0; i < 16; ++i){
        float xv = v[i] * inv;
        lg[row][l32 + i*32] = xv;
        xbufB[gr*512 + l32 + i*32] = f2b(xv);
    }
    __syncthreads();

    // Wy head: 2 tags per thread (l32, l32+32)
    float p0 = 0.f, p1 = 0.f;
    #pragma unroll 4
    for (int k = 0; k < 512; ++k){
        float xv = lg[row][k];
        p0 += xv * Wy[k*TAG_ + l32];
        p1 += xv * Wy[k*TAG_ + l32 + 32];
    }
    p0 += by[l32]; p1 += by[l32 + 32];
    float m2 = fmaxf(p0, p1);
    #pragma unroll
    for (int off = 16; off > 0; off >>= 1) m2 = fmaxf(m2, __shfl_xor(m2, off));
    float e0 = expf(p0 - m2), e1 = expf(p1 - m2);
    float s2 = e0 + e1;
    #pragma unroll
    for (int off = 16; off > 0; off >>= 1) s2 += __shfl_xor(s2, off);
    const float inv2 = 1.f / s2;
    out[((size_t)gr*T_ + t)*TAG_ + l32]      = e0 * inv2;
    out[((size_t)gr*T_ + t)*TAG_ + l32 + 32] = e1 * inv2;
}

extern "C" void kernel_launch(void* const* d_in, const int* in_sizes, int n_in,
                              void* d_out, int out_size, void* d_ws, size_t ws_size,
                              hipStream_t stream){
    const float* x   = (const float*)d_in[0];
    const float* x0  = (const float*)d_in[1];
    const float* s0  = (const float*)d_in[2];
    const float* W   = (const float*)d_in[3];
    const float* U   = (const float*)d_in[4];
    const float* b   = (const float*)d_in[5];
    const float* Wx  = (const float*)d_in[6];
    const float* bx  = (const float*)d_in[7];
    const float* Vr  = (const float*)d_in[8];
    const float* Vz  = (const float*)d_in[9];
    const float* Vs  = (const float*)d_in[10];
    const float* Wy  = (const float*)d_in[11];
    const float* by  = (const float*)d_in[12];
    float* out = (float*)d_out;

    char* ws = (char*)d_ws;
    size_t off = 0;
    auto alloc = [&](size_t bytes) -> size_t {
        size_t o = off; off = (off + bytes + 255) & ~(size_t)255; return o;
    };
    unsigned short* Wcat = (unsigned short*)(ws + alloc((size_t)K3_*2048*2));
    unsigned short* Ust  = (unsigned short*)(ws + alloc((size_t)HID_*HID_*2));
    unsigned short* Wxt  = (unsigned short*)(ws + alloc((size_t)OUT_*HID_*2));
    unsigned short* xbufB= (unsigned short*)(ws + alloc((size_t)B_*OUT_*2));
    unsigned short* s_b  = (unsigned short*)(ws + alloc((size_t)B_*HID_*2));
    unsigned short* rs_b = (unsigned short*)(ws + alloc((size_t)B_*HID_*2));
    float* s_f    = (float*)(ws + alloc((size_t)2*B_*HID_*4));
    float* pre_z  = (float*)(ws + alloc((size_t)B_*HID_*4));
    float* pre_xs = (float*)(ws + alloc((size_t)B_*HID_*4));
    unsigned short* xb16 = (unsigned short*)(ws + alloc((size_t)B_*T_*DIM_*2));
    int use_xb = (off <= ws_size) ? 1 : 0;

    // Wcat[col][2048]: k 0..511 = W; 512..1023 = V{r,z,s} by col-section; 1024..2047 = U_rz (cols<2048)
    k_tr<<<dim3(16, 96), 256, 0, stream>>>(Wcat,                           2048, W,  K3_,  0);
    k_tr<<<dim3(16, 32), 256, 0, stream>>>(Wcat + 512,                     2048, Vr, HID_, 0);
    k_tr<<<dim3(16, 32), 256, 0, stream>>>(Wcat + (size_t)1024*2048 + 512, 2048, Vz, HID_, 0);
    k_tr<<<dim3(16, 32), 256, 0, stream>>>(Wcat + (size_t)2048*2048 + 512, 2048, Vs, HID_, 0);
    k_tr<<<dim3(32, 64), 256, 0, stream>>>(Wcat + 1024,                    2048, U,  K3_,  0);
    k_tr<<<dim3(32, 32), 256, 0, stream>>>(Ust,                            1024, U,  K3_,  2048);
    k_tr<<<dim3(32, 16), 256, 0, stream>>>(Wxt,                            1024, Wx, OUT_, 0);
    if (use_xb){
        int n4 = B_*T_*DIM_/4;
        k_cvtx<<<(n4 + 255)/256, 256, 0, stream>>>((const float4*)x, (ushort4*)xb16, n4);
    }
    k_init<<<(B_*HID_ + 255)/256, 256, 0, stream>>>(x0, s0, xbufB, s_f, s_b);

    for (int t = 0; t < T_; ++t){
        float* spf = s_f + (size_t)(t & 1)*(B_*HID_);
        float* snf = s_f + (size_t)((t & 1)^1)*(B_*HID_);
        k_gA <<<96, 512, 0, stream>>>(xb16, x, use_xb, Wcat, b, xbufB, s_b, spf,
                                      rs_b, pre_z, pre_xs, t);
        k_gB <<<32, 512, 0, stream>>>(Ust, rs_b, pre_z, pre_xs, spf, snf, s_b);
        k_gCD<<< 8, 512, 0, stream>>>(Wxt, s_b, bx, Wy, by, xbufB, out, t);
    }
}

// Round 12
// 23289.156 us; speedup vs baseline: 1.1018x; 1.1018x over previous
//
#include <hip/hip_runtime.h>
#include <math.h>

#define B_    128
#define T_    256
#define DIM_  512
#define HID_  1024
#define OUT_  512
#define TAG_  64
#define K3_   3072

typedef float f32x4 __attribute__((ext_vector_type(4)));
typedef short bf16x8 __attribute__((ext_vector_type(8)));
typedef unsigned uint32x4 __attribute__((ext_vector_type(4)));

#define MFMA(a,b,c) __builtin_amdgcn_mfma_f32_16x16x32_bf16(a,b,c,0,0,0)

__device__ __forceinline__ unsigned short f2b(float f){
    unsigned int u = __float_as_uint(f);
    u = (u + 0x7fffu + ((u >> 16) & 1u)) >> 16;   // RNE
    return (unsigned short)u;
}
__device__ __forceinline__ float hardsig(float x){
    return fminf(fmaxf(0.2f*x + 0.5f, 0.f), 1.f);
}
__device__ __forceinline__ uint32x4 ld16(const void* p){
    return *(const uint32x4*)p;
}
__device__ __forceinline__ uint32x4 pack8f(const float* p){
    float4 a = *(const float4*)p;
    float4 b = *(const float4*)(p + 4);
    uint32x4 r;
    r.x = ((unsigned)f2b(a.y) << 16) | f2b(a.x);
    r.y = ((unsigned)f2b(a.w) << 16) | f2b(a.z);
    r.z = ((unsigned)f2b(b.y) << 16) | f2b(b.x);
    r.w = ((unsigned)f2b(b.w) << 16) | f2b(b.z);
    return r;
}

// ---------- prep kernels ----------
__global__ __launch_bounds__(256) void k_tr(
    unsigned short* __restrict__ dst, int dstride,
    const float* __restrict__ src, int ld, int col_off)
{
    __shared__ float tile[32][33];
    const int kb = blockIdx.x * 32, nb = blockIdx.y * 32;
    const int tx = threadIdx.x & 31, ty = threadIdx.x >> 5;
    #pragma unroll
    for (int i = 0; i < 4; ++i){
        int kl = ty + i*8;
        tile[kl][tx] = src[(size_t)(kb + kl)*ld + col_off + nb + tx];
    }
    __syncthreads();
    #pragma unroll
    for (int i = 0; i < 4; ++i){
        int nl = ty + i*8;
        dst[(size_t)(nb + nl)*dstride + kb + tx] = f2b(tile[tx][nl]);
    }
}
__global__ __launch_bounds__(256) void k_cvtx(
    const float4* __restrict__ src, ushort4* __restrict__ dst, int n4)
{
    int i = blockIdx.x * 256 + threadIdx.x;
    if (i < n4){
        float4 v = src[i];
        ushort4 o;
        o.x = f2b(v.x); o.y = f2b(v.y); o.z = f2b(v.z); o.w = f2b(v.w);
        dst[i] = o;
    }
}
__global__ __launch_bounds__(256) void k_init(
    const float* __restrict__ x0, const float* __restrict__ s0,
    unsigned short* __restrict__ xbufB, float* __restrict__ s_f,
    unsigned short* __restrict__ s_b)
{
    int i = blockIdx.x * 256 + threadIdx.x;
    if (i < B_*OUT_) xbufB[i] = f2b(x0[i]);
    if (i < B_*HID_){ s_f[i] = s0[i]; s_b[i] = f2b(s0[i]); }
}

// ===== K1: phase A + K-split U_s partials — 96 WGs x 512 =====
// np (strip of 128 cols) = wg%24, mp = wg/24. r-strips (np<8) also compute
// partial_np[rows][1024] = rs[:, np*128:+128] @ U_s[np*128:+128, :].
__global__ __launch_bounds__(512) void k_gA2(
    const unsigned short* __restrict__ xb16, const float* __restrict__ xf, int use_xb,
    const unsigned short* __restrict__ Wcat, const float* __restrict__ bias,
    const unsigned short* __restrict__ xbufB, const unsigned short* __restrict__ s_bb,
    const float* __restrict__ spf, const unsigned short* __restrict__ Ust,
    float* __restrict__ partial, float* __restrict__ pre_z,
    float* __restrict__ pre_xs, int t)
{
    __shared__ __align__(16) char smem[131072];
    __shared__ __align__(16) char rs_sm[8192];     // [32][128] bf16, XOR-swizzled
    const int wg   = blockIdx.x;
    const int tid  = threadIdx.x;
    const int lane = tid & 63;
    const int wv   = tid >> 6;
    const int l15  = lane & 15;
    const int kch  = lane >> 4;
    const int mt   = wv >> 2;
    const int ns   = wv & 3;
    const int axor = l15 & 7;

    const int npA = wg % 24, mpA = wg / 24;
    const int m0A = mpA*32, cA = npA*128, nsegA = npA >> 3;   // 0=r 1=z 2=xs

    if (nsegA < 2){
        #pragma unroll
        for (int j = 0; j < 16; ++j){
            const int c = tid + j*512, row = c >> 8, k16 = c & 255;
            const int gr = m0A + row;
            uint32x4 v;
            if (k16 < 64)       v = ld16(xbufB + gr*512 + k16*8);
            else if (k16 < 128){
                if (use_xb)     v = ld16(xb16 + ((size_t)gr*T_ + t)*DIM_ + (k16-64)*8);
                else            v = pack8f(xf + ((size_t)gr*T_ + t)*DIM_ + (k16-64)*8);
            } else              v = ld16(s_bb + gr*1024 + (k16-128)*8);
            *(uint32x4*)(smem + row*4096 + ((k16 ^ (row & 7)) << 4)) = v;
        }
    } else {
        #pragma unroll
        for (int j = 0; j < 8; ++j){
            const int c = tid + j*512, row = c >> 7, k16 = c & 127;
            const int gr = m0A + row;
            uint32x4 v;
            if (k16 < 64)       v = ld16(xbufB + gr*512 + k16*8);
            else {
                if (use_xb)     v = ld16(xb16 + ((size_t)gr*T_ + t)*DIM_ + (k16-64)*8);
                else            v = pack8f(xf + ((size_t)gr*T_ + t)*DIM_ + (k16-64)*8);
            }
            *(uint32x4*)(smem + row*4096 + ((k16 ^ (row & 7)) << 4)) = v;
        }
    }
    __syncthreads();

    const int c0 = cA + ns*32;
    const int kmax = (nsegA < 2) ? 2048 : 1024;
    const unsigned short* bp0 = Wcat + (size_t)(c0 + l15)*2048 + kch*8;
    const unsigned short* bp1 = bp0 + (size_t)16*2048;
    f32x4 acc0 = {0.f,0.f,0.f,0.f}, acc1 = {0.f,0.f,0.f,0.f};
    const int abase = (mt*16 + l15)*4096;
    #pragma unroll 8
    for (int kb = 0; kb < kmax; kb += 32){
        bf16x8 a = *(const bf16x8*)(smem + abase + ((((kb>>3)+kch) ^ axor) << 4));
        acc0 = MFMA(a, *(const bf16x8*)(bp0 + kb), acc0);
        acc1 = MFMA(a, *(const bf16x8*)(bp1 + kb), acc1);
    }
    const int rbA = m0A + mt*16 + kch*4;
    if (nsegA == 0){
        // rs -> LDS only (consumed by the partial GEMM below)
        #pragma unroll
        for (int h = 0; h < 2; ++h){
            f32x4 acc = h ? acc1 : acc0;
            const int kloc = ns*32 + h*16 + l15;     // local r-col 0..127
            const int col  = cA + kloc;              // global r-col
            const float bv = bias[col];
            #pragma unroll
            for (int q = 0; q < 4; ++q){
                const int rloc = mt*16 + kch*4 + q;  // local row 0..31
                float rs = hardsig(acc[q] + bv) * spf[(size_t)(m0A+rloc)*1024 + col];
                *(unsigned short*)(rs_sm + rloc*256 + (((kloc>>3) ^ (rloc&7)) << 4)
                                   + (kloc&7)*2) = f2b(rs);
            }
        }
        __syncthreads();
        // partial GEMM: [32 x 128] @ Ust[np-chunk][1024] -> partial_np[32][1024]
        const int pc0 = wv*128;                       // this wave's 128 out cols
        f32x4 pa[2][8];
        #pragma unroll
        for (int m2 = 0; m2 < 2; ++m2)
            #pragma unroll
            for (int nt = 0; nt < 8; ++nt) pa[m2][nt] = (f32x4){0.f,0.f,0.f,0.f};
        #pragma unroll
        for (int ks = 0; ks < 4; ++ks){
            bf16x8 a0 = *(const bf16x8*)(rs_sm + l15*256        + (((ks*4+kch) ^ (l15&7)) << 4));
            bf16x8 a1 = *(const bf16x8*)(rs_sm + (16+l15)*256   + (((ks*4+kch) ^ (l15&7)) << 4));
            #pragma unroll
            for (int nt = 0; nt < 8; ++nt){
                bf16x8 b = *(const bf16x8*)(Ust + (size_t)(pc0 + nt*16 + l15)*1024
                                            + npA*128 + ks*32 + kch*8);
                pa[0][nt] = MFMA(a0, b, pa[0][nt]);
                pa[1][nt] = MFMA(a1, b, pa[1][nt]);
            }
        }
        #pragma unroll
        for (int m2 = 0; m2 < 2; ++m2){
            #pragma unroll
            for (int nt = 0; nt < 8; ++nt){
                #pragma unroll
                for (int q = 0; q < 4; ++q){
                    const int grow = m0A + m2*16 + kch*4 + q;
                    partial[((size_t)npA*128 + grow)*1024 + pc0 + nt*16 + l15] = pa[m2][nt][q];
                }
            }
        }
    } else if (nsegA == 1){
        #pragma unroll
        for (int h = 0; h < 2; ++h){
            f32x4 acc = h ? acc1 : acc0;
            const int col = c0 + h*16 + l15;
            const float bv = bias[col];
            #pragma unroll
            for (int q = 0; q < 4; ++q)
                pre_z[(size_t)(rbA+q)*1024 + (col - 1024)] = acc[q] + bv;
        }
    } else {
        #pragma unroll
        for (int h = 0; h < 2; ++h){
            f32x4 acc = h ? acc1 : acc0;
            const int col = c0 + h*16 + l15;
            const float bv = bias[col];
            #pragma unroll
            for (int q = 0; q < 4; ++q)
                pre_xs[(size_t)(rbA+q)*1024 + (col - 2048)] = acc[q] + bv;
        }
    }
}

// ===== K2: Bfin + C + D — 32 WGs x 512, 4 rows each =====
__global__ __launch_bounds__(512) void k_gBCD(
    const float* __restrict__ partial,
    const float* __restrict__ pre_z, const float* __restrict__ pre_xs,
    const float* __restrict__ spf,
    const unsigned short* __restrict__ Wxt, const float* __restrict__ bx,
    const float* __restrict__ Wy,   const float* __restrict__ by,
    float* __restrict__ snf, unsigned short* __restrict__ s_bb,
    unsigned short* __restrict__ xbufB, float* __restrict__ out, int t)
{
    __shared__ __align__(16) unsigned short s_sm[16*1024];  // rows 4..15 garbage (harmless)
    __shared__ float lg[4][516];
    __shared__ float xsm[4][512];
    const int g    = blockIdx.x;     // rows 4g..4g+3
    const int r0   = g*4;
    const int tid  = threadIdx.x;
    const int wv   = tid >> 6;
    const int l15  = tid & 15;
    const int kch  = (tid & 63) >> 4;

    // ---- Bfin: s_t = (1-z)s + z tanh(xs + sum partials) ----
    #pragma unroll
    for (int i = 0; i < 8; ++i){
        const int idx = tid + i*512;
        const int row = idx >> 10, col = idx & 1023;
        const int gr  = r0 + row;
        const size_t gidx = (size_t)gr*1024 + col;
        float ps = 0.f;
        #pragma unroll
        for (int np = 0; np < 8; ++np)
            ps += partial[((size_t)np*128 + gr)*1024 + col];
        float s1  = tanhf(pre_xs[gidx] + ps);
        float z   = hardsig(pre_z[gidx]);
        float snv = (1.f - z)*spf[gidx] + z*s1;
        snf[gidx]  = snv;
        unsigned short sb = f2b(snv);
        s_bb[gidx] = sb;
        // LDS swizzled write
        *(unsigned short*)((char*)s_sm + row*2048 + (((col>>3) ^ (row&7)) << 4)
                           + (col&7)*2) = sb;
    }
    __syncthreads();

    // ---- C: logits = s @ Wx + bx (wave wv -> cols wv*64..+63) ----
    const int c0w = wv*64;
    f32x4 ac[4];
    #pragma unroll
    for (int nt = 0; nt < 4; ++nt) ac[nt] = (f32x4){0.f,0.f,0.f,0.f};
    #pragma unroll 8
    for (int kb = 0; kb < 32; ++kb){
        bf16x8 a = *(const bf16x8*)((char*)s_sm + l15*2048
                                    + (((kb*4+kch) ^ (l15&7)) << 4));
        #pragma unroll
        for (int nt = 0; nt < 4; ++nt){
            bf16x8 b = *(const bf16x8*)(Wxt + (size_t)(c0w + nt*16 + l15)*1024
                                        + kb*32 + kch*8);
            ac[nt] = MFMA(a, b, ac[nt]);
        }
    }
    if (kch == 0){
        #pragma unroll
        for (int nt = 0; nt < 4; ++nt){
            const int col = c0w + nt*16 + l15;
            #pragma unroll
            for (int q = 0; q < 4; ++q)
                lg[q][col] = ac[nt][q] + bx[col];   // valid rows are 0..3 (kch==0)
        }
    }
    __syncthreads();

    // ---- D1: softmax(logits) -> x_t (one wave per row) ----
    if (tid < 256){
        const int row = tid >> 6, l = tid & 63;
        const int gr  = r0 + row;
        float v[8];
        float mx = -3.0e38f;
        #pragma unroll
        for (int i = 0; i < 8; ++i){ v[i] = lg[row][l + i*64]; mx = fmaxf(mx, v[i]); }
        #pragma unroll
        for (int off = 32; off > 0; off >>= 1) mx = fmaxf(mx, __shfl_xor(mx, off));
        float s = 0.f;
        #pragma unroll
        for (int i = 0; i < 8; ++i){ v[i] = expf(v[i] - mx); s += v[i]; }
        #pragma unroll
        for (int off = 32; off > 0; off >>= 1) s += __shfl_xor(s, off);
        const float inv = 1.f / s;
        #pragma unroll
        for (int i = 0; i < 8; ++i){
            float xv = v[i] * inv;
            xsm[row][l + i*64] = xv;
            xbufB[gr*512 + l + i*64] = f2b(xv);
        }
    }
    __syncthreads();

    // ---- D2: out = softmax(x_t @ Wy + by) ----
    if (tid < 256){
        const int row = tid >> 6, tag = tid & 63;
        const int gr  = r0 + row;
        float p0=0.f, p1=0.f, p2=0.f, p3=0.f;
        #pragma unroll 4
        for (int k = 0; k < 512; k += 4){
            p0 += xsm[row][k+0] * Wy[(k+0)*TAG_ + tag];
            p1 += xsm[row][k+1] * Wy[(k+1)*TAG_ + tag];
            p2 += xsm[row][k+2] * Wy[(k+2)*TAG_ + tag];
            p3 += xsm[row][k+3] * Wy[(k+3)*TAG_ + tag];
        }
        float p = p0 + p1 + p2 + p3 + by[tag];
        float wm = p;
        #pragma unroll
        for (int off = 32; off > 0; off >>= 1) wm = fmaxf(wm, __shfl_xor(wm, off));
        float e = expf(p - wm);
        float sm = e;
        #pragma unroll
        for (int off = 32; off > 0; off >>= 1) sm += __shfl_xor(sm, off);
        out[((size_t)gr*T_ + t)*TAG_ + tag] = e / sm;
    }
}

extern "C" void kernel_launch(void* const* d_in, const int* in_sizes, int n_in,
                              void* d_out, int out_size, void* d_ws, size_t ws_size,
                              hipStream_t stream){
    const float* x   = (const float*)d_in[0];
    const float* x0  = (const float*)d_in[1];
    const float* s0  = (const float*)d_in[2];
    const float* W   = (const float*)d_in[3];
    const float* U   = (const float*)d_in[4];
    const float* b   = (const float*)d_in[5];
    const float* Wx  = (const float*)d_in[6];
    const float* bx  = (const float*)d_in[7];
    const float* Vr  = (const float*)d_in[8];
    const float* Vz  = (const float*)d_in[9];
    const float* Vs  = (const float*)d_in[10];
    const float* Wy  = (const float*)d_in[11];
    const float* by  = (const float*)d_in[12];
    float* out = (float*)d_out;

    char* ws = (char*)d_ws;
    size_t off = 0;
    auto alloc = [&](size_t bytes) -> size_t {
        size_t o = off; off = (off + bytes + 255) & ~(size_t)255; return o;
    };
    unsigned short* Wcat = (unsigned short*)(ws + alloc((size_t)K3_*2048*2));
    unsigned short* Ust  = (unsigned short*)(ws + alloc((size_t)HID_*HID_*2));
    unsigned short* Wxt  = (unsigned short*)(ws + alloc((size_t)OUT_*HID_*2));
    unsigned short* xbufB= (unsigned short*)(ws + alloc((size_t)B_*OUT_*2));
    unsigned short* s_b  = (unsigned short*)(ws + alloc((size_t)B_*HID_*2));
    float* partial= (float*)(ws + alloc((size_t)8*B_*HID_*4));     // 4 MB
    float* s_f    = (float*)(ws + alloc((size_t)2*B_*HID_*4));
    float* pre_z  = (float*)(ws + alloc((size_t)B_*HID_*4));
    float* pre_xs = (float*)(ws + alloc((size_t)B_*HID_*4));
    unsigned short* xb16 = (unsigned short*)(ws + alloc((size_t)B_*T_*DIM_*2));
    int use_xb = (off <= ws_size) ? 1 : 0;

    // Wcat[col][2048]: k 0..511 = W; 512..1023 = V{r,z,s} by col-section; 1024..2047 = U_rz (cols<2048)
    k_tr<<<dim3(16, 96), 256, 0, stream>>>(Wcat,                           2048, W,  K3_,  0);
    k_tr<<<dim3(16, 32), 256, 0, stream>>>(Wcat + 512,                     2048, Vr, HID_, 0);
    k_tr<<<dim3(16, 32), 256, 0, stream>>>(Wcat + (size_t)1024*2048 + 512, 2048, Vz, HID_, 0);
    k_tr<<<dim3(16, 32), 256, 0, stream>>>(Wcat + (size_t)2048*2048 + 512, 2048, Vs, HID_, 0);
    k_tr<<<dim3(32, 64), 256, 0, stream>>>(Wcat + 1024,                    2048, U,  K3_,  0);
    k_tr<<<dim3(32, 32), 256, 0, stream>>>(Ust,                            1024, U,  K3_,  2048);
    k_tr<<<dim3(32, 16), 256, 0, stream>>>(Wxt,                            1024, Wx, OUT_, 0);
    if (use_xb){
        int n4 = B_*T_*DIM_/4;
        k_cvtx<<<(n4 + 255)/256, 256, 0, stream>>>((const float4*)x, (ushort4*)xb16, n4);
    }
    k_init<<<(B_*HID_ + 255)/256, 256, 0, stream>>>(x0, s0, xbufB, s_f, s_b);

    for (int t = 0; t < T_; ++t){
        float* spf = s_f + (size_t)(t & 1)*(B_*HID_);
        float* snf = s_f + (size_t)((t & 1)^1)*(B_*HID_);
        k_gA2 <<<96, 512, 0, stream>>>(xb16, x, use_xb, Wcat, b, xbufB, s_b, spf,
                                       Ust, partial, pre_z, pre_xs, t);
        k_gBCD<<<32, 512, 0, stream>>>(partial, pre_z, pre_xs, spf, Wxt, bx, Wy, by,
                                       snf, s_b, xbufB, out, t);
    }
}